// Round 6
// baseline (5363.205 us; speedup 1.0000x reference)
//
#include <hip/hip_runtime.h>
#include <hip/hip_bf16.h>
#include <cstdint>
#include <cstddef>

typedef short v8s __attribute__((ext_vector_type(8)));
typedef float v4f __attribute__((ext_vector_type(4)));
typedef float v16f __attribute__((ext_vector_type(16)));

#define TT 128
#define BB 256
#define HH 1024
#define II 256
#define CC 1000

// short-offsets inside the swizzled-weight region of ws
#define OFF_WHH0 0u
#define OFF_WHH1 1048576u
#define OFF_WIH1 2097152u
#define OFF_WIH0 3145728u
#define WSW_SHORTS 3407872u

#define NJ 16      // 64-col tiles per (layer,group)
#define FSTR 16    // uints per flag line (64B, one line per producer)
#define FAM_UINTS (4 * NJ * FSTR)          // per family (4 groups)
#define FLAG_UINTS (3 * FAM_UINTS)         // flA, flX, flB
#define FLAG_BYTES (FLAG_UINTS * 4)

__device__ __forceinline__ unsigned short f2bf(float f) {
  unsigned int u = __float_as_uint(f);
  u += 0x7fffu + ((u >> 16) & 1u);  // RTNE
  return (unsigned short)(u >> 16);
}
__device__ __forceinline__ float bf2f(unsigned short s) {
  return __uint_as_float((unsigned int)s << 16);
}
__device__ __forceinline__ float fast_tanh(float x) {
  float ax = fabsf(x);
  float e = __expf(-2.0f * ax);
  float r = 1.0f - 2.0f * e / (1.0f + e);
  return x < 0.0f ? -r : r;
}
__device__ __forceinline__ v16f mfma32(v8s a, v8s b, v16f c) {
  return __builtin_amdgcn_mfma_f32_32x32x16_bf16(a, b, c, 0, 0, 0);
}

// Poll NJ=16 monotonic flags (64B-strided lines) until all >= need.
// Pure __hip_atomic_load (agent scope -> LLC-coherent), NO inline asm.
__device__ __forceinline__ void pollf(const unsigned int* base, unsigned int need,
                                      int lane) {
  const unsigned int* p = base + (size_t)(lane & 15) * FSTR;
  for (;;) {
    unsigned int v = __hip_atomic_load(p, __ATOMIC_RELAXED, __HIP_MEMORY_SCOPE_AGENT);
    if (__ballot(v >= need) == ~0ull) return;
    __builtin_amdgcn_s_sleep(1);
  }
}
__device__ __forceinline__ void waitcnt_vm0() {
  asm volatile("s_waitcnt vmcnt(0)" ::: "memory");  // wait-only; proven r2/r3
}

// Pre-swizzle W (fp32 [N][K]) into 32x32x16 B-fragment order:
// out[((jt32*(K/16)+kk)*64+lane)*8+j] = bf16(W[jt32*32+(lane&31)][kk*16+(lane>>5)*8+j])
__global__ void swizzle_w(const float* __restrict__ W, unsigned short* __restrict__ out,
                          int K, int total) {
  int idx = blockIdx.x * 256 + threadIdx.x;
  if (idx >= total) return;
  int lane = idx & 63;
  int rest = idx >> 6;
  int KC = K >> 4;
  int kk = rest & (KC - 1);
  int jt = rest / KC;
  int row = jt * 32 + (lane & 31);
  int k0 = kk * 16 + (lane >> 5) * 8;
  const float* src = W + (size_t)row * K + k0;
  float4 f0 = *(const float4*)src;
  float4 f1 = *(const float4*)(src + 4);
  unsigned short o[8] = {f2bf(f0.x), f2bf(f0.y), f2bf(f0.z), f2bf(f0.w),
                         f2bf(f1.x), f2bf(f1.y), f2bf(f1.z), f2bf(f1.w)};
  *(v8s*)(out + (size_t)idx * 8) = *(const v8s*)o;
}

// xp = bias + x @ Wih0^T, bf16, stored in consumer D-fragment layout:
// xp[(((t*4+g)*32+jt32)*2+tile)*1024 + lane*16 + r]
__global__ __launch_bounds__(256, 1) void xp_kernel(
    const float* __restrict__ x, const unsigned short* __restrict__ wih_sw,
    const float* __restrict__ bih0, const float* __restrict__ bhh0,
    unsigned short* __restrict__ xp) {
  __shared__ unsigned short lA[16 * 64 * 8];
  const int tid = threadIdx.x;
  const int lane = tid & 63, wave = tid >> 6;
  const int bi = blockIdx.x;           // 1024 blocks: (t*4+g)*2+tile
  const int t = bi >> 3, g = (bi >> 1) & 3, tile = bi & 1;
  const int b0 = g * 64 + tile * 32;
  #pragma unroll
  for (int s = 0; s < 4; ++s) {
    int idx = s * 256 + tid;
    int row = idx >> 5, kg = idx & 31;
    const float* src = x + ((size_t)(b0 + row) * TT + t) * II + kg * 8;
    float4 f0 = *(const float4*)src;
    float4 f1 = *(const float4*)(src + 4);
    unsigned short o[8] = {f2bf(f0.x), f2bf(f0.y), f2bf(f0.z), f2bf(f0.w),
                           f2bf(f1.x), f2bf(f1.y), f2bf(f1.z), f2bf(f1.w)};
    int kk = kg >> 1, hf = kg & 1;
    *(v8s*)(lA + ((size_t)kk * 64 + hf * 32 + row) * 8) = *(const v8s*)o;
  }
  __syncthreads();
  const int col = lane & 31;
  for (int jj = 0; jj < 8; ++jj) {
    int jt = wave * 8 + jj;
    float bias = bih0[jt * 32 + col] + bhh0[jt * 32 + col];
    v16f acc;
    #pragma unroll
    for (int r = 0; r < 16; ++r) acc[r] = bias;
    const unsigned short* bw = wih_sw + (size_t)jt * 8192;
    #pragma unroll 4
    for (int kk = 0; kk < 16; ++kk) {
      v8s a = *(const v8s*)(lA + ((size_t)kk * 64 + lane) * 8);
      v8s b = *(const v8s*)(bw + ((size_t)kk * 64 + lane) * 8);
      acc = mfma32(a, b, acc);
    }
    unsigned short o[16];
    #pragma unroll
    for (int r = 0; r < 16; ++r) o[r] = f2bf(acc[r]);
    unsigned short* dst = xp + ((size_t)((t * 4 + g) * 32 + jt) * 2 + tile) * 1024 + lane * 16;
    *(v8s*)dst = *(const v8s*)o;
    *(v8s*)(dst + 8) = *(const v8s*)(o + 8);
  }
}

// Fused 2-layer RNN. Grid 128 blocks, 256 threads (4 waves).
// blockIdx&7 = xsel = layer*4+g (XCD locality HINT only); jt = blockIdx>>3 (64 cols).
// Waves: tile = wave&1 (32-row half), kh = wave>>1 (K half).
// All cross-block signals + h stores are agent-scope atomics (LLC-coherent,
// correct under any XCD mapping). Plain 16B loads only for fresh t-indexed slots.
template <int XPON, int BIGH2>
__global__ __launch_bounds__(256, 1) void rnn_fused(
    const float* __restrict__ x, const unsigned short* __restrict__ wsw,
    const unsigned short* __restrict__ xp,
    const float* __restrict__ bih0, const float* __restrict__ bhh0,
    const float* __restrict__ bih1, const float* __restrict__ bhh1,
    unsigned short* __restrict__ hbuf, unsigned short* __restrict__ h2buf,
    unsigned int* flags) {
  __shared__ float lds_acc[4 * 1024];            // 16 KB: (tile,ct) partials
  __shared__ unsigned short lds_pack[64 * 72];   // 9 KB: padded h transpose

  const int tid = threadIdx.x;
  const int xsel = blockIdx.x & 7;
  const int layer = xsel >> 2;
  const int g = xsel & 3;
  const int jt = blockIdx.x >> 3;
  const int lane = tid & 63;
  const int wave = tid >> 6;
  const int tile = wave & 1;
  const int kh = wave >> 1;
  const int col = lane & 31;
  const int half = lane >> 5;
  const int j0 = jt * 64;

  // B-fragment base pointers (pre-swizzled, jt32 = jt*2 + ct)
  const unsigned short* whh = wsw + (layer ? OFF_WHH1 : OFF_WHH0);
  const unsigned short* wB0 = whh + ((size_t)(jt * 2 + 0) * 64) * 512 + lane * 8;
  const unsigned short* wB1 = whh + ((size_t)(jt * 2 + 1) * 64) * 512 + lane * 8;
  const unsigned short* wI0;
  const unsigned short* wI1;
  if (layer) {
    wI0 = wsw + OFF_WIH1 + ((size_t)(jt * 2 + 0) * 64) * 512 + lane * 8;
    wI1 = wsw + OFF_WIH1 + ((size_t)(jt * 2 + 1) * 64) * 512 + lane * 8;
  } else {
    wI0 = wsw + OFF_WIH0 + ((size_t)(jt * 2 + 0) * 16) * 512 + lane * 8;
    wI1 = wsw + OFF_WIH0 + ((size_t)(jt * 2 + 1) * 16) * 512 + lane * 8;
  }

  float bs0 = 0.0f, bs1 = 0.0f;
  if (layer == 1) {
    bs0 = bih1[j0 + col] + bhh1[j0 + col];
    bs1 = bih1[j0 + 32 + col] + bhh1[j0 + 32 + col];
  } else if (!XPON) {
    bs0 = bih0[j0 + col] + bhh0[j0 + col];
    bs1 = bih0[j0 + 32 + col] + bhh0[j0 + 32 + col];
  }

  const int arow = g * 64 + tile * 32 + col;
  unsigned int* flA_g = flags + (size_t)g * NJ * FSTR;
  unsigned int* flX_g = flags + FAM_UINTS + (size_t)g * NJ * FSTR;
  unsigned int* flB_g = flags + 2 * FAM_UINTS + (size_t)g * NJ * FSTR;

  // xp prefetch (layer0 kh0): 2 col-tiles × 16 bf16
  v8s xc00 = {}, xc01 = {}, xc10 = {}, xc11 = {};
  const unsigned short* xpb =
      xp + (((size_t)g * 32 + jt * 2) * 2 + tile) * 1024 + lane * 16;
  if (XPON && layer == 0 && kh == 0) {
    xc00 = *(const v8s*)xpb;          xc01 = *(const v8s*)(xpb + 8);
    xc10 = *(const v8s*)(xpb + 2048); xc11 = *(const v8s*)(xpb + 2056);
  }

  for (int t = 0; t < TT; ++t) {
    v16f a0 = {}, a1 = {};

    if (layer == 0) {
      if (kh == 0) {
        if (XPON) {
          union { v8s v[2]; unsigned short u[16]; } u0, u1;
          u0.v[0] = xc00; u0.v[1] = xc01;
          u1.v[0] = xc10; u1.v[1] = xc11;
          #pragma unroll
          for (int r = 0; r < 16; ++r) { a0[r] = bf2f(u0.u[r]); a1[r] = bf2f(u1.u[r]); }
        } else {
          #pragma unroll
          for (int r = 0; r < 16; ++r) { a0[r] = bs0; a1[r] = bs1; }
          const float* xr = x + ((size_t)arow * TT + t) * II + half * 8;
          #pragma unroll 4
          for (int kk = 0; kk < 16; ++kk) {
            float4 f0 = *(const float4*)(xr + kk * 16);
            float4 f1 = *(const float4*)(xr + kk * 16 + 4);
            unsigned short o[8] = {f2bf(f0.x), f2bf(f0.y), f2bf(f0.z), f2bf(f0.w),
                                   f2bf(f1.x), f2bf(f1.y), f2bf(f1.z), f2bf(f1.w)};
            v8s a = *(const v8s*)o;
            a0 = mfma32(a, *(const v8s*)(wI0 + kk * 512), a0);
            a1 = mfma32(a, *(const v8s*)(wI1 + kk * 512), a1);
          }
        }
        if (t > 0) {
          pollf(flA_g, (unsigned int)t, lane);
          const unsigned short* hr = hbuf + ((size_t)t * BB + arow) * HH + half * 8;
          #pragma unroll 8
          for (int kk = 0; kk < 32; ++kk) {
            v8s a = *(const v8s*)(hr + kk * 16);
            a0 = mfma32(a, *(const v8s*)(wB0 + kk * 512), a0);
            a1 = mfma32(a, *(const v8s*)(wB1 + kk * 512), a1);
          }
        }
        if (XPON) {  // prefetch next step (off critical chain)
          int tn = (t + 1 < TT) ? (t + 1) : (TT - 1);
          const unsigned short* nx = xpb + (size_t)tn * 262144;
          xc00 = *(const v8s*)nx;          xc01 = *(const v8s*)(nx + 8);
          xc10 = *(const v8s*)(nx + 2048); xc11 = *(const v8s*)(nx + 2056);
        }
      } else {
        if (t > 0) {
          pollf(flA_g, (unsigned int)t, lane);
          const unsigned short* hr = hbuf + ((size_t)t * BB + arow) * HH + half * 8;
          #pragma unroll 8
          for (int kk = 32; kk < 64; ++kk) {
            v8s a = *(const v8s*)(hr + kk * 16);
            a0 = mfma32(a, *(const v8s*)(wB0 + kk * 512), a0);
            a1 = mfma32(a, *(const v8s*)(wB1 + kk * 512), a1);
          }
        }
      }
    } else {
      if (kh == 0) {
        #pragma unroll
        for (int r = 0; r < 16; ++r) { a0[r] = bs0; a1[r] = bs1; }
        pollf(flX_g, (unsigned int)(t + 1), lane);
        const unsigned short* hr = hbuf + ((size_t)(t + 1) * BB + arow) * HH + half * 8;
        #pragma unroll 8
        for (int kk = 0; kk < 64; ++kk) {
          v8s a = *(const v8s*)(hr + kk * 16);
          a0 = mfma32(a, *(const v8s*)(wI0 + kk * 512), a0);
          a1 = mfma32(a, *(const v8s*)(wI1 + kk * 512), a1);
        }
      } else {
        if (t > 0) {
          pollf(flB_g, (unsigned int)t, lane);
          const int slot_r = BIGH2 ? (t - 1) : ((t - 1) & 1);
          const unsigned short* hr =
              h2buf + ((size_t)slot_r * BB + arow) * HH + half * 8;
          if (BIGH2) {
            #pragma unroll 8
            for (int kk = 0; kk < 64; ++kk) {
              v8s a = *(const v8s*)(hr + kk * 16);
              a0 = mfma32(a, *(const v8s*)(wB0 + kk * 512), a0);
              a1 = mfma32(a, *(const v8s*)(wB1 + kk * 512), a1);
            }
          } else {
            // parity slots are address-reused -> bypass caches (LLC atomics)
            #pragma unroll 8
            for (int kk = 0; kk < 64; ++kk) {
              const unsigned long long* p = (const unsigned long long*)(hr + kk * 16);
              unsigned long long lo = __hip_atomic_load(p, __ATOMIC_RELAXED, __HIP_MEMORY_SCOPE_AGENT);
              unsigned long long hi = __hip_atomic_load(p + 1, __ATOMIC_RELAXED, __HIP_MEMORY_SCOPE_AGENT);
              union { unsigned long long q[2]; v8s v; } u;
              u.q[0] = lo; u.q[1] = hi;
              a0 = mfma32(u.v, *(const v8s*)(wB0 + kk * 512), a0);
              a1 = mfma32(u.v, *(const v8s*)(wB1 + kk * 512), a1);
            }
          }
        }
      }
    }

    // ---- cross-wave K reduction (16B lane stride, conflict-free) ----
    if (kh == 1) {
      float* d0 = lds_acc + (tile * 2 + 0) * 1024;
      float* d1 = lds_acc + (tile * 2 + 1) * 1024;
      #pragma unroll
      for (int r4 = 0; r4 < 4; ++r4) {
        *(float4*)(d0 + r4 * 256 + lane * 4) =
            make_float4(a0[r4 * 4], a0[r4 * 4 + 1], a0[r4 * 4 + 2], a0[r4 * 4 + 3]);
        *(float4*)(d1 + r4 * 256 + lane * 4) =
            make_float4(a1[r4 * 4], a1[r4 * 4 + 1], a1[r4 * 4 + 2], a1[r4 * 4 + 3]);
      }
    }
    __syncthreads();

    // ---- sum + tanh + transpose to LDS (row-major bf16, padded stride 72) ----
    if (kh == 0) {
      const float* s0 = lds_acc + (tile * 2 + 0) * 1024;
      const float* s1 = lds_acc + (tile * 2 + 1) * 1024;
      #pragma unroll
      for (int r4 = 0; r4 < 4; ++r4) {
        float4 p0 = *(const float4*)(s0 + r4 * 256 + lane * 4);
        float4 p1 = *(const float4*)(s1 + r4 * 256 + lane * 4);
        float q0[4] = {p0.x, p0.y, p0.z, p0.w};
        float q1[4] = {p1.x, p1.y, p1.z, p1.w};
        #pragma unroll
        for (int q = 0; q < 4; ++q) {
          int r = r4 * 4 + q;
          int row_l = tile * 32 + q + 8 * r4 + 4 * half;
          lds_pack[row_l * 72 + col] = f2bf(fast_tanh(a0[r] + q0[q]));
          lds_pack[row_l * 72 + 32 + col] = f2bf(fast_tanh(a1[r] + q1[q]));
        }
      }
    }
    __syncthreads();

    // ---- packed h store: 4 × 8B agent-scope atomic stores per thread ----
    {
      int row_l = tid >> 2, cg = tid & 3;
      const unsigned long long* sp =
          (const unsigned long long*)(lds_pack + row_l * 72 + cg * 16);
      int slot_w = layer ? (BIGH2 ? t : (t & 1)) : (t + 1);
      unsigned long long* hout = (unsigned long long*)(
          (layer ? h2buf : hbuf) +
          ((size_t)slot_w * BB + g * 64 + row_l) * HH + j0 + cg * 16);
      #pragma unroll
      for (int q = 0; q < 4; ++q)
        __hip_atomic_store(hout + q, sp[q], __ATOMIC_RELAXED, __HIP_MEMORY_SCOPE_AGENT);
    }
    waitcnt_vm0();       // own stores globally visible
    __syncthreads();     // whole block done
    if (tid == 0) {
      if (layer == 0) {
        __hip_atomic_store(flA_g + jt * FSTR, (unsigned int)(t + 1),
                           __ATOMIC_RELAXED, __HIP_MEMORY_SCOPE_AGENT);
        __hip_atomic_store(flX_g + jt * FSTR, (unsigned int)(t + 1),
                           __ATOMIC_RELAXED, __HIP_MEMORY_SCOPE_AGENT);
      } else {
        __hip_atomic_store(flB_g + jt * FSTR, (unsigned int)(t + 1),
                           __ATOMIC_RELAXED, __HIP_MEMORY_SCOPE_AGENT);
      }
    }
  }
}

// out[b][c] = h2_last[b][:] . fcW[c][:] + fcb[c]
__global__ __launch_bounds__(256, 1) void fc_kernel(
    const unsigned short* __restrict__ h2, const float* __restrict__ fcW,
    const float* __restrict__ fcb, float* __restrict__ out) {
  const int tid = threadIdx.x;
  const int ct = blockIdx.x % 63;
  const int g = blockIdx.x / 63;
  const int lane = tid & 63;
  const int wave = tid >> 6;
  const int n = lane & 15;
  const int quad = lane >> 4;
  const int c = ct * 16 + n;
  const int cs = c < CC ? c : CC - 1;
  const float bias = fcb[cs];
  v4f acc = {bias, bias, bias, bias};
  const unsigned short* hr = h2 + (size_t)(g * 64 + wave * 16 + n) * HH + quad * 8;
  const float* wr = fcW + (size_t)cs * HH + quad * 8;
  #pragma unroll 8
  for (int kk = 0; kk < HH / 32; ++kk) {
    v8s a = *(const v8s*)(hr + kk * 32);
    float4 f0 = *(const float4*)(wr + kk * 32);
    float4 f1 = *(const float4*)(wr + kk * 32 + 4);
    v8s b;
    b[0] = (short)f2bf(f0.x); b[1] = (short)f2bf(f0.y);
    b[2] = (short)f2bf(f0.z); b[3] = (short)f2bf(f0.w);
    b[4] = (short)f2bf(f1.x); b[5] = (short)f2bf(f1.y);
    b[6] = (short)f2bf(f1.z); b[7] = (short)f2bf(f1.w);
    acc = __builtin_amdgcn_mfma_f32_16x16x32_bf16(a, b, acc, 0, 0, 0);
  }
  if (c < CC) {
    const int b0 = g * 64 + wave * 16 + quad * 4;
    #pragma unroll
    for (int i = 0; i < 4; ++i) out[(size_t)(b0 + i) * CC + c] = acc[i];
  }
}

extern "C" void kernel_launch(void* const* d_in, const int* in_sizes, int n_in,
                              void* d_out, int out_size, void* d_ws, size_t ws_size,
                              hipStream_t stream) {
  (void)in_sizes; (void)n_in; (void)out_size;
  const float* x    = (const float*)d_in[0];
  const float* Wih0 = (const float*)d_in[1];
  const float* Whh0 = (const float*)d_in[2];
  const float* bih0 = (const float*)d_in[3];
  const float* bhh0 = (const float*)d_in[4];
  const float* Wih1 = (const float*)d_in[5];
  const float* Whh1 = (const float*)d_in[6];
  const float* bih1 = (const float*)d_in[7];
  const float* bhh1 = (const float*)d_in[8];
  const float* fcW  = (const float*)d_in[9];
  const float* fcb  = (const float*)d_in[10];

  const size_t hbuf_elems = (size_t)(TT + 1) * BB * HH;   // 129 slots
  const size_t h2_full = (size_t)TT * BB * HH;
  const size_t h2_par  = (size_t)2 * BB * HH;
  const size_t xp_elems = (size_t)TT * BB * HH;

  const size_t needA = (WSW_SHORTS + hbuf_elems + h2_full + xp_elems) * 2 + FLAG_BYTES;
  const size_t needB = (WSW_SHORTS + hbuf_elems + h2_par + xp_elems) * 2 + FLAG_BYTES;
  const bool tierA = ws_size >= needA;
  const bool tierB = !tierA && ws_size >= needB;

  unsigned short* wsw = (unsigned short*)d_ws;
  unsigned short* hbuf = wsw + WSW_SHORTS;
  unsigned short* h2buf = hbuf + hbuf_elems;
  unsigned short* xpbuf = h2buf + (tierA ? h2_full : h2_par);
  unsigned int* flags = (unsigned int*)(xpbuf + ((tierA || tierB) ? xp_elems : 0));

  hipMemsetAsync(flags, 0, FLAG_BYTES, stream);
  swizzle_w<<<512, 256, 0, stream>>>(Whh0, wsw + OFF_WHH0, HH, 32 * 64 * 64);
  swizzle_w<<<512, 256, 0, stream>>>(Whh1, wsw + OFF_WHH1, HH, 32 * 64 * 64);
  swizzle_w<<<512, 256, 0, stream>>>(Wih1, wsw + OFF_WIH1, HH, 32 * 64 * 64);
  swizzle_w<<<128, 256, 0, stream>>>(Wih0, wsw + OFF_WIH0, II, 32 * 16 * 64);

  if (tierA || tierB)
    xp_kernel<<<1024, 256, 0, stream>>>(x, wsw + OFF_WIH0, bih0, bhh0, xpbuf);

  if (tierA) {
    rnn_fused<1, 1><<<128, 256, 0, stream>>>(
        x, wsw, xpbuf, bih0, bhh0, bih1, bhh1, hbuf, h2buf, flags);
  } else if (tierB) {
    rnn_fused<1, 0><<<128, 256, 0, stream>>>(
        x, wsw, xpbuf, bih0, bhh0, bih1, bhh1, hbuf, h2buf, flags);
  } else {
    rnn_fused<0, 0><<<128, 256, 0, stream>>>(
        x, wsw, xpbuf, bih0, bhh0, bih1, bhh1, hbuf, h2buf, flags);
  }

  const unsigned short* h2last = h2buf + (size_t)(tierA ? (TT - 1) : 1) * BB * HH;
  fc_kernel<<<63 * 4, 256, 0, stream>>>(h2last, fcW, fcb, (float*)d_out);
}

// Round 7
// 1771.344 us; speedup vs baseline: 3.0278x; 3.0278x over previous
//
#include <hip/hip_runtime.h>
#include <hip/hip_bf16.h>
#include <cstdint>
#include <cstddef>

typedef short v8s __attribute__((ext_vector_type(8)));
typedef float v4f __attribute__((ext_vector_type(4)));
typedef float v16f __attribute__((ext_vector_type(16)));

#define TT 128
#define BB 256
#define HH 1024
#define II 256
#define CC 1000

// short-offsets inside the swizzled-weight region of ws
#define OFF_WHH0 0u
#define OFF_WHH1 1048576u
#define OFF_WIH1 2097152u
#define OFF_WIH0 3145728u
#define WSW_SHORTS 3407872u

#define NJ 32      // 32-col tiles per (layer,group)
#define FSTR 16    // uints per flag line (64B)
#define FAM_UINTS (4 * NJ * FSTR)          // per family (4 groups)
#define FLAG_UINTS (3 * FAM_UINTS)         // flA, flX, flB
#define FLAG_BYTES (FLAG_UINTS * 4)

#define NCHUNK_LDS 50                       // Whh chunks staged in LDS (50 KB)

__device__ __forceinline__ unsigned short f2bf(float f) {
  unsigned int u = __float_as_uint(f);
  u += 0x7fffu + ((u >> 16) & 1u);  // RTNE
  return (unsigned short)(u >> 16);
}
__device__ __forceinline__ float bf2f(unsigned short s) {
  return __uint_as_float((unsigned int)s << 16);
}
__device__ __forceinline__ float fast_tanh(float x) {
  float ax = fabsf(x);
  float e = __expf(-2.0f * ax);
  float r = 1.0f - 2.0f * e / (1.0f + e);
  return x < 0.0f ? -r : r;
}
__device__ __forceinline__ v16f mfma32(v8s a, v8s b, v16f c) {
  return __builtin_amdgcn_mfma_f32_32x32x16_bf16(a, b, c, 0, 0, 0);
}

// Poll NJ=32 monotonic flags (64B-strided lines) until all >= need.
// Pure __hip_atomic_load (LLC-coherent). NO asm loads (round-5 lesson).
__device__ __forceinline__ void pollf(const unsigned int* base, unsigned int need,
                                      int lane) {
  const unsigned int* p = base + (size_t)(lane & 31) * FSTR;
  for (;;) {
    unsigned int v = __hip_atomic_load(p, __ATOMIC_RELAXED, __HIP_MEMORY_SCOPE_AGENT);
    if (__ballot(v >= need) == ~0ull) return;
    __builtin_amdgcn_s_sleep(1);
  }
}
// 16B LLC write-through store. Input-only asm constraints (safe; the round-5
// bug was the load asm's output/address overlap, not stores).
__device__ __forceinline__ void store16_llc(unsigned short* addr, v8s val) {
  asm volatile("global_store_dwordx4 %0, %1, off sc0 sc1"
               :: "v"(addr), "v"(val) : "memory");
}
__device__ __forceinline__ void waitcnt_vm0() {
  asm volatile("s_waitcnt vmcnt(0)" ::: "memory");
}

// Pre-swizzle W (fp32 [N][K]) into 32x32x16 B-fragment order:
// out[((jt*(K/16)+kk)*64+lane)*8+j] = bf16(W[jt*32+(lane&31)][kk*16+(lane>>5)*8+j])
__global__ void swizzle_w(const float* __restrict__ W, unsigned short* __restrict__ out,
                          int K, int total) {
  int idx = blockIdx.x * 256 + threadIdx.x;
  if (idx >= total) return;
  int lane = idx & 63;
  int rest = idx >> 6;
  int KC = K >> 4;
  int kk = rest & (KC - 1);
  int jt = rest / KC;
  int row = jt * 32 + (lane & 31);
  int k0 = kk * 16 + (lane >> 5) * 8;
  const float* src = W + (size_t)row * K + k0;
  float4 f0 = *(const float4*)src;
  float4 f1 = *(const float4*)(src + 4);
  unsigned short o[8] = {f2bf(f0.x), f2bf(f0.y), f2bf(f0.z), f2bf(f0.w),
                         f2bf(f1.x), f2bf(f1.y), f2bf(f1.z), f2bf(f1.w)};
  *(v8s*)(out + (size_t)idx * 8) = *(const v8s*)o;
}

// xp = bias + x @ Wih0^T, bf16, consumer D-fragment layout:
// xp[(((t*4+g)*32+jt)*2+tile)*1024 + lane*16 + r]   (proven round 6)
__global__ __launch_bounds__(256, 1) void xp_kernel(
    const float* __restrict__ x, const unsigned short* __restrict__ wih_sw,
    const float* __restrict__ bih0, const float* __restrict__ bhh0,
    unsigned short* __restrict__ xp) {
  __shared__ unsigned short lA[16 * 64 * 8];
  const int tid = threadIdx.x;
  const int lane = tid & 63, wave = tid >> 6;
  const int bi = blockIdx.x;           // 1024 blocks: (t*4+g)*2+tile
  const int t = bi >> 3, g = (bi >> 1) & 3, tile = bi & 1;
  const int b0 = g * 64 + tile * 32;
  #pragma unroll
  for (int s = 0; s < 4; ++s) {
    int idx = s * 256 + tid;
    int row = idx >> 5, kg = idx & 31;
    const float* src = x + ((size_t)(b0 + row) * TT + t) * II + kg * 8;
    float4 f0 = *(const float4*)src;
    float4 f1 = *(const float4*)(src + 4);
    unsigned short o[8] = {f2bf(f0.x), f2bf(f0.y), f2bf(f0.z), f2bf(f0.w),
                           f2bf(f1.x), f2bf(f1.y), f2bf(f1.z), f2bf(f1.w)};
    int kk = kg >> 1, hf = kg & 1;
    *(v8s*)(lA + ((size_t)kk * 64 + hf * 32 + row) * 8) = *(const v8s*)o;
  }
  __syncthreads();
  const int col = lane & 31;
  for (int jj = 0; jj < 8; ++jj) {
    int jt = wave * 8 + jj;
    float bias = bih0[jt * 32 + col] + bhh0[jt * 32 + col];
    v16f acc;
    #pragma unroll
    for (int r = 0; r < 16; ++r) acc[r] = bias;
    const unsigned short* bw = wih_sw + (size_t)jt * 8192;
    #pragma unroll 4
    for (int kk = 0; kk < 16; ++kk) {
      v8s a = *(const v8s*)(lA + ((size_t)kk * 64 + lane) * 8);
      v8s b = *(const v8s*)(bw + ((size_t)kk * 64 + lane) * 8);
      acc = mfma32(a, b, acc);
    }
    unsigned short o[16];
    #pragma unroll
    for (int r = 0; r < 16; ++r) o[r] = f2bf(acc[r]);
    unsigned short* dst = xp + ((size_t)((t * 4 + g) * 32 + jt) * 2 + tile) * 1024 + lane * 16;
    *(v8s*)dst = *(const v8s*)o;
    *(v8s*)(dst + 8) = *(const v8s*)(o + 8);
  }
}

// Fused 2-layer RNN. Grid 256 blocks (1/CU), 256 threads (4 waves).
// blockIdx&7 = xsel = layer*4+g (XCD hint only); jt = blockIdx>>3 (32-col tile).
// Waves: tile = wave&1 (32-row half), kh = wave>>1 (K half / matrix split).
// Whh staged in LDS (chunks 0..49); h stores: LDS transpose + 256×16B sc0 sc1
// stores; all signals agent-scope atomics (correct under any XCD mapping).
template <int XPON, int BIGH2>
__global__ __launch_bounds__(256, 1) void rnn_fused(
    const float* __restrict__ x, const unsigned short* __restrict__ wsw,
    const unsigned short* __restrict__ xp,
    const float* __restrict__ bih0, const float* __restrict__ bhh0,
    const float* __restrict__ bih1, const float* __restrict__ bhh1,
    unsigned short* __restrict__ hbuf, unsigned short* __restrict__ h2buf,
    unsigned int* flags) {
  __shared__ unsigned short lds_whh[NCHUNK_LDS * 512];  // 50 KB
  __shared__ float lds_acc[2 * 1024];                   // 8 KB (per-tile partials)
  __shared__ unsigned short lds_pack[64 * 40];          // 5 KB padded transpose

  const int tid = threadIdx.x;
  const int xsel = blockIdx.x & 7;
  const int layer = xsel >> 2;
  const int g = xsel & 3;
  const int jt = blockIdx.x >> 3;
  const int lane = tid & 63;
  const int wave = tid >> 6;
  const int tile = wave & 1;
  const int kh = wave >> 1;
  const int col = lane & 31;
  const int half = lane >> 5;
  const int j0 = jt * 32;

  const unsigned short* whh_tile =
      wsw + (layer ? OFF_WHH1 : OFF_WHH0) + (size_t)jt * 32768;
  const unsigned short* wih_tile =
      layer ? (wsw + OFF_WIH1 + (size_t)jt * 32768)
            : (wsw + OFF_WIH0 + (size_t)jt * 8192);

  for (int i = tid * 8; i < NCHUNK_LDS * 512; i += 2048)
    *(v8s*)(lds_whh + i) = *(const v8s*)(whh_tile + i);

  float bias = 0.0f;
  if (layer == 1) bias = bih1[j0 + col] + bhh1[j0 + col];
  else if (!XPON) bias = bih0[j0 + col] + bhh0[j0 + col];
  __syncthreads();

  const int arow = g * 64 + tile * 32 + col;
  unsigned int* flA_g = flags + (size_t)g * NJ * FSTR;
  unsigned int* flX_g = flags + FAM_UINTS + (size_t)g * NJ * FSTR;
  unsigned int* flB_g = flags + 2 * FAM_UINTS + (size_t)g * NJ * FSTR;

  // xp prefetch (layer0 kh0 waves)
  v8s xc0 = {}, xc1 = {};
  const unsigned short* xpb =
      xp + (((size_t)g * 32 + jt) * 2 + tile) * 1024 + lane * 16;
  if (XPON && layer == 0 && kh == 0) {
    xc0 = *(const v8s*)xpb;
    xc1 = *(const v8s*)(xpb + 8);
  }

  for (int t = 0; t < TT; ++t) {
    v16f acc = {};

    if (layer == 0) {
      if (kh == 0) {
        if (XPON) {
          union { v8s v[2]; unsigned short u[16]; } xu;
          xu.v[0] = xc0; xu.v[1] = xc1;
          #pragma unroll
          for (int r = 0; r < 16; ++r) acc[r] = bf2f(xu.u[r]);
        } else {
          #pragma unroll
          for (int r = 0; r < 16; ++r) acc[r] = bias;
          const float* xr = x + ((size_t)arow * TT + t) * II + half * 8;
          #pragma unroll 4
          for (int kk = 0; kk < 16; ++kk) {
            float4 f0 = *(const float4*)(xr + kk * 16);
            float4 f1 = *(const float4*)(xr + kk * 16 + 4);
            unsigned short o[8] = {f2bf(f0.x), f2bf(f0.y), f2bf(f0.z), f2bf(f0.w),
                                   f2bf(f1.x), f2bf(f1.y), f2bf(f1.z), f2bf(f1.w)};
            acc = mfma32(*(const v8s*)o,
                         *(const v8s*)(wih_tile + ((size_t)kk * 64 + lane) * 8), acc);
          }
        }
        if (t > 0) {
          pollf(flA_g, (unsigned int)t, lane);
          const unsigned short* hr = hbuf + ((size_t)t * BB + arow) * HH + half * 8;
          #pragma unroll 8
          for (int kk = 0; kk < 32; ++kk) {
            v8s a = *(const v8s*)(hr + kk * 16);
            v8s b = *(const v8s*)(lds_whh + ((size_t)kk * 64 + lane) * 8);
            acc = mfma32(a, b, acc);
          }
        }
        if (XPON) {  // prefetch next step (off critical chain)
          int tn = (t + 1 < TT) ? (t + 1) : (TT - 1);
          const unsigned short* nx = xpb + (size_t)tn * 262144;
          xc0 = *(const v8s*)nx;
          xc1 = *(const v8s*)(nx + 8);
        }
      } else {
        if (t > 0) {
          pollf(flA_g, (unsigned int)t, lane);
          const unsigned short* hr = hbuf + ((size_t)t * BB + arow) * HH + half * 8;
          #pragma unroll 8
          for (int kk = 32; kk < NCHUNK_LDS; ++kk) {
            v8s a = *(const v8s*)(hr + kk * 16);
            v8s b = *(const v8s*)(lds_whh + ((size_t)kk * 64 + lane) * 8);
            acc = mfma32(a, b, acc);
          }
          #pragma unroll
          for (int kk = NCHUNK_LDS; kk < 64; ++kk) {
            v8s a = *(const v8s*)(hr + kk * 16);
            v8s b = *(const v8s*)(whh_tile + ((size_t)kk * 64 + lane) * 8);
            acc = mfma32(a, b, acc);
          }
        }
      }
    } else {
      if (kh == 0) {
        #pragma unroll
        for (int r = 0; r < 16; ++r) acc[r] = bias;
        pollf(flX_g, (unsigned int)(t + 1), lane);
        const unsigned short* hr = hbuf + ((size_t)(t + 1) * BB + arow) * HH + half * 8;
        #pragma unroll 8
        for (int kk = 0; kk < 64; ++kk) {
          v8s a = *(const v8s*)(hr + kk * 16);
          v8s b = *(const v8s*)(wih_tile + ((size_t)kk * 64 + lane) * 8);
          acc = mfma32(a, b, acc);
        }
      } else {
        if (t > 0) {
          pollf(flB_g, (unsigned int)t, lane);
          const int slot_r = BIGH2 ? (t - 1) : ((t - 1) & 1);
          const unsigned short* hr =
              h2buf + ((size_t)slot_r * BB + arow) * HH + half * 8;
          if (BIGH2) {
            #pragma unroll 8
            for (int kk = 0; kk < NCHUNK_LDS; ++kk) {
              v8s a = *(const v8s*)(hr + kk * 16);
              v8s b = *(const v8s*)(lds_whh + ((size_t)kk * 64 + lane) * 8);
              acc = mfma32(a, b, acc);
            }
            #pragma unroll
            for (int kk = NCHUNK_LDS; kk < 64; ++kk) {
              v8s a = *(const v8s*)(hr + kk * 16);
              v8s b = *(const v8s*)(whh_tile + ((size_t)kk * 64 + lane) * 8);
              acc = mfma32(a, b, acc);
            }
          } else {
            // parity slots are address-reused -> LLC atomic loads
            #pragma unroll 8
            for (int kk = 0; kk < 64; ++kk) {
              const unsigned long long* p = (const unsigned long long*)(hr + kk * 16);
              unsigned long long lo = __hip_atomic_load(p, __ATOMIC_RELAXED, __HIP_MEMORY_SCOPE_AGENT);
              unsigned long long hi = __hip_atomic_load(p + 1, __ATOMIC_RELAXED, __HIP_MEMORY_SCOPE_AGENT);
              union { unsigned long long q[2]; v8s v; } u;
              u.q[0] = lo; u.q[1] = hi;
              v8s b = (kk < NCHUNK_LDS)
                          ? *(const v8s*)(lds_whh + ((size_t)kk * 64 + lane) * 8)
                          : *(const v8s*)(whh_tile + ((size_t)kk * 64 + lane) * 8);
              acc = mfma32(u.v, b, acc);
            }
          }
        }
      }
    }

    // ---- cross-wave K reduction (16B lane stride, conflict-free; r3-proven) ----
    if (kh == 1) {
      float* dst = lds_acc + tile * 1024;
      #pragma unroll
      for (int r4 = 0; r4 < 4; ++r4)
        *(float4*)(dst + r4 * 256 + lane * 4) =
            make_float4(acc[r4 * 4], acc[r4 * 4 + 1], acc[r4 * 4 + 2], acc[r4 * 4 + 3]);
    }
    __syncthreads();

    // ---- sum + tanh + transpose to LDS (row-major bf16, stride 40) ----
    if (kh == 0) {
      const float* srcp = lds_acc + tile * 1024;
      #pragma unroll
      for (int r4 = 0; r4 < 4; ++r4) {
        float4 part = *(const float4*)(srcp + r4 * 256 + lane * 4);
        float pv[4] = {part.x, part.y, part.z, part.w};
        #pragma unroll
        for (int q = 0; q < 4; ++q) {
          int r = r4 * 4 + q;
          int row_l = tile * 32 + q + 8 * r4 + 4 * half;
          lds_pack[row_l * 40 + col] = f2bf(fast_tanh(acc[r] + pv[q]));
        }
      }
    }
    __syncthreads();

    // ---- packed h store: ONE 16B sc0 sc1 store per thread (256/block) ----
    {
      int row_l = tid >> 2, cg = tid & 3;
      v8s hv = *(const v8s*)(lds_pack + row_l * 40 + cg * 8);
      int slot_w = layer ? (BIGH2 ? t : (t & 1)) : (t + 1);
      unsigned short* hout = (layer ? h2buf : hbuf) +
          ((size_t)slot_w * BB + g * 64 + row_l) * HH + j0 + cg * 8;
      store16_llc(hout, hv);
    }
    waitcnt_vm0();       // own stores at LLC
    __syncthreads();     // whole block done
    if (tid == 0) {
      if (layer == 0) {
        __hip_atomic_store(flA_g + jt * FSTR, (unsigned int)(t + 1),
                           __ATOMIC_RELAXED, __HIP_MEMORY_SCOPE_AGENT);
        __hip_atomic_store(flX_g + jt * FSTR, (unsigned int)(t + 1),
                           __ATOMIC_RELAXED, __HIP_MEMORY_SCOPE_AGENT);
      } else {
        __hip_atomic_store(flB_g + jt * FSTR, (unsigned int)(t + 1),
                           __ATOMIC_RELAXED, __HIP_MEMORY_SCOPE_AGENT);
      }
    }
  }
}

// out[b][c] = h2_last[b][:] . fcW[c][:] + fcb[c]
__global__ __launch_bounds__(256, 1) void fc_kernel(
    const unsigned short* __restrict__ h2, const float* __restrict__ fcW,
    const float* __restrict__ fcb, float* __restrict__ out) {
  const int tid = threadIdx.x;
  const int ct = blockIdx.x % 63;
  const int g = blockIdx.x / 63;
  const int lane = tid & 63;
  const int wave = tid >> 6;
  const int n = lane & 15;
  const int quad = lane >> 4;
  const int c = ct * 16 + n;
  const int cs = c < CC ? c : CC - 1;
  const float bias = fcb[cs];
  v4f acc = {bias, bias, bias, bias};
  const unsigned short* hr = h2 + (size_t)(g * 64 + wave * 16 + n) * HH + quad * 8;
  const float* wr = fcW + (size_t)cs * HH + quad * 8;
  #pragma unroll 8
  for (int kk = 0; kk < HH / 32; ++kk) {
    v8s a = *(const v8s*)(hr + kk * 32);
    float4 f0 = *(const float4*)(wr + kk * 32);
    float4 f1 = *(const float4*)(wr + kk * 32 + 4);
    v8s b;
    b[0] = (short)f2bf(f0.x); b[1] = (short)f2bf(f0.y);
    b[2] = (short)f2bf(f0.z); b[3] = (short)f2bf(f0.w);
    b[4] = (short)f2bf(f1.x); b[5] = (short)f2bf(f1.y);
    b[6] = (short)f2bf(f1.z); b[7] = (short)f2bf(f1.w);
    acc = __builtin_amdgcn_mfma_f32_16x16x32_bf16(a, b, acc, 0, 0, 0);
  }
  if (c < CC) {
    const int b0 = g * 64 + wave * 16 + quad * 4;
    #pragma unroll
    for (int i = 0; i < 4; ++i) out[(size_t)(b0 + i) * CC + c] = acc[i];
  }
}

extern "C" void kernel_launch(void* const* d_in, const int* in_sizes, int n_in,
                              void* d_out, int out_size, void* d_ws, size_t ws_size,
                              hipStream_t stream) {
  (void)in_sizes; (void)n_in; (void)out_size;
  const float* x    = (const float*)d_in[0];
  const float* Wih0 = (const float*)d_in[1];
  const float* Whh0 = (const float*)d_in[2];
  const float* bih0 = (const float*)d_in[3];
  const float* bhh0 = (const float*)d_in[4];
  const float* Wih1 = (const float*)d_in[5];
  const float* Whh1 = (const float*)d_in[6];
  const float* bih1 = (const float*)d_in[7];
  const float* bhh1 = (const float*)d_in[8];
  const float* fcW  = (const float*)d_in[9];
  const float* fcb  = (const float*)d_in[10];

  const size_t hbuf_elems = (size_t)(TT + 1) * BB * HH;   // 129 slots
  const size_t h2_full = (size_t)TT * BB * HH;
  const size_t h2_par  = (size_t)2 * BB * HH;
  const size_t xp_elems = (size_t)TT * BB * HH;

  const size_t needA = (WSW_SHORTS + hbuf_elems + h2_full + xp_elems) * 2 + FLAG_BYTES;
  const size_t needB = (WSW_SHORTS + hbuf_elems + h2_par + xp_elems) * 2 + FLAG_BYTES;
  const bool tierA = ws_size >= needA;
  const bool tierB = !tierA && ws_size >= needB;

  unsigned short* wsw = (unsigned short*)d_ws;
  unsigned short* hbuf = wsw + WSW_SHORTS;
  unsigned short* h2buf = hbuf + hbuf_elems;
  unsigned short* xpbuf = h2buf + (tierA ? h2_full : h2_par);
  unsigned int* flags = (unsigned int*)(xpbuf + ((tierA || tierB) ? xp_elems : 0));

  hipMemsetAsync(flags, 0, FLAG_BYTES, stream);
  swizzle_w<<<512, 256, 0, stream>>>(Whh0, wsw + OFF_WHH0, HH, 32 * 64 * 64);
  swizzle_w<<<512, 256, 0, stream>>>(Whh1, wsw + OFF_WHH1, HH, 32 * 64 * 64);
  swizzle_w<<<512, 256, 0, stream>>>(Wih1, wsw + OFF_WIH1, HH, 32 * 64 * 64);
  swizzle_w<<<128, 256, 0, stream>>>(Wih0, wsw + OFF_WIH0, II, 32 * 16 * 64);

  if (tierA || tierB)
    xp_kernel<<<1024, 256, 0, stream>>>(x, wsw + OFF_WIH0, bih0, bhh0, xpbuf);

  if (tierA) {
    rnn_fused<1, 1><<<256, 256, 0, stream>>>(
        x, wsw, xpbuf, bih0, bhh0, bih1, bhh1, hbuf, h2buf, flags);
  } else if (tierB) {
    rnn_fused<1, 0><<<256, 256, 0, stream>>>(
        x, wsw, xpbuf, bih0, bhh0, bih1, bhh1, hbuf, h2buf, flags);
  } else {
    rnn_fused<0, 0><<<256, 256, 0, stream>>>(
        x, wsw, xpbuf, bih0, bhh0, bih1, bhh1, hbuf, h2buf, flags);
  }

  const unsigned short* h2last = h2buf + (size_t)(tierA ? (TT - 1) : 1) * BB * HH;
  fc_kernel<<<63 * 4, 256, 0, stream>>>(h2last, fcW, fcb, (float*)d_out);
}